// Round 5
// baseline (668.803 us; speedup 1.0000x reference)
//
#include <hip/hip_runtime.h>
#include <math.h>

#define IMH 256
#define IMW 256
#define NBT 8
#define NF  64
#define HW  65536

// power-iteration batching
#define TSZ 16
#define MB 10          // iterations per batch
#define NBATCH 30      // 30*10 = 300 total
#define HALO (2*MB)    // 20 (operator radius 2 per step)
// LDS buffer: 60 rows x 68 cols (+4 float front guard, +4 tail).
// BROW=68: row stride 272 B -> strips within a wave land 16 banks apart
// (2-way aliasing, free). Data cols in-row [0,64); [64,68) stay zero.
// Region (56x56) at rows [2,58); central 16x16 tile rows [22,38),
// in-row cols [24,40).
#define BROW 68
#define BUFSZ (60*BROW + 8)

// pi_batch: 512 threads (8 waves -> 2 waves/SIMD; the R4 256-thread version
// was latency-bound at 1 wave/SIMD). 2-row strips, 28 active of 32.
#define PIT 512
#define NPART 2048     // 256 blocks x 8 waves per level

// out0 filter-split (fused into pi_batch as extra blocks)
#define NG0 8
#define FG0 (NF / NG0)   // 8 filters per group
#define OB_TOTAL 2048    // 32 yb x 8 g x 8 b  (8 rows per sub-block)
#define OBPB 69          // out0 sub-blocks per pi launch: 30*69 >= 2048

// ws float offsets
#define WS_SM   0      // 81: masked-operator table Sm[dr][dq]
#define WS_K5   81     // 25: fused interior 5x5 kernel
#define WS_ET   106    // 5: top-edge correction kernel (applied at gy==0)
#define WS_EB   111    // 5: bottom-edge (gy==IMH-1)
#define WS_EL   116    // 5: left-edge (gx==0, vertical)
#define WS_ER   121    // 5: right-edge (gx==IMW-1, vertical)
#define WS_C4   126    // 4: corner add-backs TL,TR,BL,BR
#define WS_LIP2 431
#define WS_TAU  432
#define WS_SIGMA 433
// incremental stopping-rule state (replayed exactly as reference while_loop)
#define WS_ST_K    434   // iterations consumed so far (float-encoded int)
#define WS_ST_VAL  435   // current val (ratio estimate)
#define WS_ST_STOP 436   // 1.0f once rel<1e-4 or k>=300

// -------------------------------------------------------------------------
// Setup: build Sm, K5, and edge-correction tables from w. (unchanged)
// -------------------------------------------------------------------------
__global__ void setup_kernel(const float* __restrict__ w, float* __restrict__ ws) {
    int t = threadIdx.x;
    __shared__ float smS[81];
    if (t < 81) {
        int a = t / 9, bq = t % 9;
        int dry = a / 3 - 1, drx = a % 3 - 1;
        int dqy = bq / 3 - 1, dqx = bq % 3 - 1;
        int r_idx = (1 - dry) * 3 + (1 - drx);
        int q_idx = (dqy + 1) * 3 + (dqx + 1);
        float s = 0.f;
        for (int f = 0; f < NF; ++f) s += w[f * 9 + r_idx] * w[f * 9 + q_idx];
        smS[t] = s;
        ws[WS_SM + t] = s;
    }
    __syncthreads();
    if (t < 25) {
        int dy = t / 5 - 2, dx = t % 5 - 2;
        float k = 0.f;
        for (int a = 0; a < 9; ++a) {
            int dry = a / 3 - 1, drx = a % 3 - 1;
            for (int bq = 0; bq < 9; ++bq) {
                int dqy = bq / 3 - 1, dqx = bq % 3 - 1;
                if (dry + dqy == dy && drx + dqx == dx) k += smS[a * 9 + bq];
            }
        }
        ws[WS_K5 + t] = k;
    }
    if (t == 0) {
        for (int dd = 0; dd < 5; ++dd) {
            int dx = dd - 2;
            float et = 0.f, eb = 0.f, el = 0.f, er = 0.f;
            for (int dr = -1; dr <= 1; ++dr) {
                int dq = dx - dr;
                if (dq < -1 || dq > 1) continue;
                et += smS[(0 * 3 + dr + 1) * 9 + (2 * 3 + dq + 1)];   // dry=-1,dqy=+1
                eb += smS[(2 * 3 + dr + 1) * 9 + (0 * 3 + dq + 1)];   // dry=+1,dqy=-1
                el += smS[((dr + 1) * 3 + 0) * 9 + ((dq + 1) * 3 + 2)]; // drx=-1,dqx=+1
                er += smS[((dr + 1) * 3 + 2) * 9 + ((dq + 1) * 3 + 0)]; // drx=+1,dqx=-1
            }
            ws[WS_ET + dd] = et;
            ws[WS_EB + dd] = eb;
            ws[WS_EL + dd] = el;
            ws[WS_ER + dd] = er;
        }
        ws[WS_C4 + 0] = smS[0 * 9 + 8];  // TL
        ws[WS_C4 + 1] = smS[2 * 9 + 6];  // TR
        ws[WS_C4 + 2] = smS[6 * 9 + 2];  // BL
        ws[WS_C4 + 3] = smS[8 * 9 + 0];  // BR
        // re-init convergence state every launch (re-poison safety)
        ws[WS_ST_K] = 0.f;
        ws[WS_ST_VAL] = 1.0f;
        ws[WS_ST_STOP] = 0.f;
    }
}

// -------------------------------------------------------------------------
// pi_batch: blocks [0,256) = one MB-step power-iteration batch on 16x16
// tiles; blocks [256, 256+OBPB) = a slice of the out0 conv_t partials
// (independent of the pi state -> runs on idle SIMDs / stub launches).
//
// pi role: 512 threads, strip = tid>>4 (2 output rows each, 28 active),
// q = tid&15 (4-col quad). Per step: 6x8 register window, 200 FMAs,
// edge corrections, zero-outside mask, 2 b128 writes.
// Dependency-cone skip at 8-row wave granularity (bit-exact).
// Early exit: block 0 folds the PREVIOUS batch's 10 level norms into the
// stopping-rule state (1-batch lag); once stopped, pi blocks return.
// -------------------------------------------------------------------------
__global__ __launch_bounds__(PIT) void pi_batch_kernel(
    float* __restrict__ ws, float* __restrict__ gbuf,
    float* __restrict__ part, float* __restrict__ part0,
    const float* __restrict__ u_in, const float* __restrict__ w,
    int batch) {
    __shared__ float bufA[BUFSZ];
    __shared__ float bufB[BUFSZ];
    __shared__ float sred[8];
    const int tid = threadIdx.x;
    const int bid = blockIdx.x;

    // ---------------- out0 conv_t role (blocks >= 256) ----------------
    if (bid >= 256) {
        const int obi = batch * OBPB + (bid - 256);
        if (obi < OB_TOTAL) {
            const int yb = obi & 31;
            const int g = (obi >> 5) & 7;
            const int b = obi >> 8;
            const int lane = tid & 63;
            const int wd = tid >> 6;              // 8 rows per sub-block
            const int y = yb * 8 + wd;
            const int x0 = lane * 4;
            float4 ct = {0.f, 0.f, 0.f, 0.f};
            const float* ub = u_in + ((size_t)b * NF + g * FG0) * HW;
            const float* wg = w + g * FG0 * 9;
#pragma unroll 4
            for (int f = 0; f < FG0; ++f) {
                const float* uf = ub + (size_t)f * HW;
                const float* wf = wg + f * 9;
#pragma unroll
                for (int dy = -1; dy <= 1; ++dy) {
                    int yy = y + dy;
                    float4 v = {0.f, 0.f, 0.f, 0.f};
                    if ((unsigned)yy < IMH)
                        v = *(const float4*)(uf + yy * IMW + x0);
                    float m1 = __shfl_up(v.w, 1);
                    if (lane == 0) m1 = 0.f;
                    float p4 = __shfl_down(v.x, 1);
                    if (lane == 63) p4 = 0.f;
                    const float w2 = wf[(1 - dy) * 3 + 2];   // dx=-1
                    const float w1 = wf[(1 - dy) * 3 + 1];   // dx= 0
                    const float w0 = wf[(1 - dy) * 3 + 0];   // dx=+1
                    ct.x += w2 * m1  + w1 * v.x + w0 * v.y;
                    ct.y += w2 * v.x + w1 * v.y + w0 * v.z;
                    ct.z += w2 * v.y + w1 * v.z + w0 * v.w;
                    ct.w += w2 * v.z + w1 * v.w + w0 * p4;
                }
            }
            *(float4*)(part0 + ((size_t)(g * NBT + b)) * HW + y * IMW + x0) = ct;
        }
        return;
    }

    // ---------------- pi role ----------------
    const int wid = tid >> 6;
    const int lane = tid & 63;
    const int q = tid & 15;
    const int strip = tid >> 4;
    const int tx = bid & 15;
    const int ty = bid >> 4;
    const float* gin = gbuf + ((batch & 1) ? HW : 0);
    float* gout      = gbuf + ((batch & 1) ? 0 : HW);

    // converged already? (state covers levels <= (batch-1)*MB)
    if (batch > 0 && ws[WS_ST_STOP] != 0.f) return;

    // block 0: fold batch-1's levels into the stopping-rule state.
    if (bid == 0 && batch > 0) {
        float k_it = ws[WS_ST_K];
        float val  = ws[WS_ST_VAL];
        float nprev = 1.0f;
        float newstop = 0.f;
        const float* pb = part + (size_t)((batch - 1) * MB) * NPART;
        for (int s = 0; s < MB; ++s) {
            const float* pp = pb + (size_t)s * NPART;
            float sm = pp[tid] + pp[tid + 512] + pp[tid + 1024] + pp[tid + 1536];
#pragma unroll
            for (int o = 32; o > 0; o >>= 1) sm += __shfl_down(sm, o, 64);
            if (lane == 0) sred[wid] = sm;
            __syncthreads();
            float tot = sred[0] + sred[1] + sred[2] + sred[3]
                      + sred[4] + sred[5] + sred[6] + sred[7];
            __syncthreads();
            float n = sqrtf(tot);
            float v = n / nprev;
            nprev = n;
            float rel = fabsf(v - val) / val;
            val = v;
            k_it += 1.f;
            if (rel < 1e-4f || k_it >= 300.f) { newstop = 1.f; break; }
        }
        if (tid == 0) {
            ws[WS_ST_K] = k_it;
            ws[WS_ST_VAL] = val;
            ws[WS_ST_STOP] = newstop;
        }
        __syncthreads();
    }

    float k5[25];
#pragma unroll
    for (int i = 0; i < 25; ++i) k5[i] = ws[WS_K5 + i];
    float et[5], eb[5], el[5], er[5], c4[4];
#pragma unroll
    for (int i = 0; i < 5; ++i) {
        et[i] = ws[WS_ET + i]; eb[i] = ws[WS_EB + i];
        el[i] = ws[WS_EL + i]; er[i] = ws[WS_ER + i];
    }
#pragma unroll
    for (int i = 0; i < 4; ++i) c4[i] = ws[WS_C4 + i];

    float inv_n;
    if (batch == 0) {
        inv_n = 1.0f / 256.0f;
    } else {
        const float* pp = part + (size_t)(batch * MB - 1) * NPART;
        float s = pp[tid] + pp[tid + 512] + pp[tid + 1024] + pp[tid + 1536];
#pragma unroll
        for (int o = 32; o > 0; o >>= 1) s += __shfl_down(s, o, 64);
        if (lane == 0) sred[wid] = s;
        __syncthreads();
        inv_n = 1.0f / sqrtf(sred[0] + sred[1] + sred[2] + sred[3]
                           + sred[4] + sred[5] + sred[6] + sred[7]);
        __syncthreads();
    }

    // load region into bufA (zeros outside image / in pads); zero bufB fully
    for (int i = tid; i < BUFSZ; i += PIT) {
        float v = 0.f;
        if (i >= 4) {
            int cell = i - 4;
            int r = cell / BROW, c = cell - r * BROW;
            if (r < 60 && c < 64) {
                int gy = ty * 16 - 22 + r;    // region row r-2 + oy
                int gx = tx * 16 - 24 + c;    // region col c-4 + ox
                if ((unsigned)gy < IMH && (unsigned)gx < IMW)
                    v = (batch == 0) ? inv_n : gin[gy * IMW + gx] * inv_n;
            }
        }
        bufA[i] = v;
        bufB[i] = 0.f;
    }
    __syncthreads();

    // per-thread invariants (2-row strips)
    const bool active = (strip < 28);
    const int r0 = 2 + 2 * strip;          // output rows r0, r0+1
    const int gy0 = ty * 16 - 22 + r0;
    const int gx0 = tx * 16 - 24 + 4 * q;
    bool iny[2], bt[2], bb[2];
#pragma unroll
    for (int k = 0; k < 2; ++k) {
        int gy = gy0 + k;
        iny[k] = ((unsigned)gy < IMH);
        bt[k] = (gy == 0);
        bb[k] = (gy == IMH - 1);
    }
    bool inx[4];
#pragma unroll
    for (int i = 0; i < 4; ++i) inx[i] = ((unsigned)(gx0 + i) < IMW);
    const bool bL = (gx0 == 0);
    const bool bR = (gx0 + 3 == IMW - 1);
    const bool central = (q >= 6 && q < 10) && (strip >= 10 && strip < 18);
    // wave row band for dependency-cone skip (8 rows per wave)
    const int wrow_lo = 2 + 8 * wid;
    const int wrow_hi = (wrow_lo + 8 < 58) ? wrow_lo + 8 : 58;

    float* cur = bufA;
    float* nxt = bufB;
#pragma unroll 1
    for (int s = 0; s < MB; ++s) {
        float pv = 0.f;
        // needed rows after this step: [2+2*(s+1), 58-2*(s+1))
        const int lo = 2 + 2 * (s + 1);
        const int hi = 58 - 2 * (s + 1);
        const bool wave_need = (wrow_lo < hi) && (wrow_hi > lo);
        if (active && wave_need) {
            // 6x8 register window: rows r0-2 .. r0+3, cols 4q-2 .. 4q+5
            float win[6][8];
            const int base = 4 + (r0 - 2) * BROW + 4 * q;
#pragma unroll
            for (int m = 0; m < 6; ++m) {
                float4 a = *(const float4*)&cur[base + m * BROW];
                float2 lo2 = *(const float2*)&cur[base + m * BROW - 2];
                float2 hi2 = *(const float2*)&cur[base + m * BROW + 4];
                win[m][0] = lo2.x; win[m][1] = lo2.y;
                win[m][2] = a.x;  win[m][3] = a.y;
                win[m][4] = a.z;  win[m][5] = a.w;
                win[m][6] = hi2.x; win[m][7] = hi2.y;
            }
            float z[2][4];
#pragma unroll
            for (int k = 0; k < 2; ++k) {
#pragma unroll
                for (int i = 0; i < 4; ++i) z[k][i] = 0.f;
#pragma unroll
                for (int j = 0; j < 5; ++j) {
#pragma unroll
                    for (int dx = 0; dx < 5; ++dx) {
                        const float kv = k5[j * 5 + dx];
                        z[k][0] += kv * win[k + j][0 + dx];
                        z[k][1] += kv * win[k + j][1 + dx];
                        z[k][2] += kv * win[k + j][2 + dx];
                        z[k][3] += kv * win[k + j][3 + dx];
                    }
                }
            }
            // image-edge corrections (outermost ring only)
#pragma unroll
            for (int k = 0; k < 2; ++k) {
                if (bt[k]) {
#pragma unroll
                    for (int i = 0; i < 4; ++i) {
                        float c = 0.f;
#pragma unroll
                        for (int d = 0; d < 5; ++d) c += et[d] * win[k + 2][i + d];
                        z[k][i] -= c;
                    }
                }
                if (bb[k]) {
#pragma unroll
                    for (int i = 0; i < 4; ++i) {
                        float c = 0.f;
#pragma unroll
                        for (int d = 0; d < 5; ++d) c += eb[d] * win[k + 2][i + d];
                        z[k][i] -= c;
                    }
                }
            }
            if (bL) {
#pragma unroll
                for (int k = 0; k < 2; ++k) {
                    float c = 0.f;
#pragma unroll
                    for (int j = 0; j < 5; ++j) c += el[j] * win[k + j][2];
                    z[k][0] -= c;
                    if (bt[k]) z[k][0] += c4[0] * win[k + 2][2];
                    if (bb[k]) z[k][0] += c4[2] * win[k + 2][2];
                }
            }
            if (bR) {
#pragma unroll
                for (int k = 0; k < 2; ++k) {
                    float c = 0.f;
#pragma unroll
                    for (int j = 0; j < 5; ++j) c += er[j] * win[k + j][5];
                    z[k][3] -= c;
                    if (bt[k]) z[k][3] += c4[1] * win[k + 2][5];
                    if (bb[k]) z[k][3] += c4[3] * win[k + 2][5];
                }
            }
            // zero-outside mask, store, central-norm partial
#pragma unroll
            for (int k = 0; k < 2; ++k) {
                float4 o;
                o.x = (iny[k] && inx[0]) ? z[k][0] : 0.f;
                o.y = (iny[k] && inx[1]) ? z[k][1] : 0.f;
                o.z = (iny[k] && inx[2]) ? z[k][2] : 0.f;
                o.w = (iny[k] && inx[3]) ? z[k][3] : 0.f;
                *(float4*)&nxt[4 + (r0 + k) * BROW + 4 * q] = o;
                if (central)
                    pv += o.x * o.x + o.y * o.y + o.z * o.z + o.w * o.w;
            }
        }
        // per-wave reduce; wave leader stores to its private slot
#pragma unroll
        for (int o = 32; o > 0; o >>= 1) pv += __shfl_down(pv, o, 64);
        if (lane == 0)
            part[(size_t)(batch * MB + s) * NPART + (bid << 3) + wid] = pv;
        __syncthreads();
        float* tmp = cur; cur = nxt; nxt = tmp;
    }

    // write central 16x16 tile (64 threads x float4)
    if (tid < 64) {
        int rr = tid >> 2, cq = tid & 3;
        float4 v = *(const float4*)&cur[4 + (22 + rr) * BROW + 24 + 4 * cq];
        int gy = ty * 16 + rr, gx = tx * 16 + 4 * cq;
        *(float4*)&gout[gy * IMW + gx] = v;
    }
}

// -------------------------------------------------------------------------
// Finalize: fold the LAST batch's levels (if the rule hasn't stopped yet),
// then compute tau/sigma.
// -------------------------------------------------------------------------
__global__ __launch_bounds__(256) void finalize_kernel(
    float* __restrict__ ws, const float* __restrict__ part,
    const float* __restrict__ beta, const float* __restrict__ log_sigma) {
    __shared__ float sr[4];
    const int tid = threadIdx.x;
    const int lane = tid & 63;
    const int wid = tid >> 6;
    float k_it = ws[WS_ST_K];
    float val  = ws[WS_ST_VAL];
    const float stop = ws[WS_ST_STOP];
    if (stop == 0.f) {
        float nprev = 1.0f;
        const float* pb = part + (size_t)((NBATCH - 1) * MB) * NPART;
        for (int s = 0; s < MB; ++s) {
            const float* pp = pb + (size_t)s * NPART;
            float sm = 0.f;
#pragma unroll
            for (int j = 0; j < 8; ++j) sm += pp[tid + 256 * j];
#pragma unroll
            for (int o = 32; o > 0; o >>= 1) sm += __shfl_down(sm, o, 64);
            if (lane == 0) sr[wid] = sm;
            __syncthreads();
            float tot = sr[0] + sr[1] + sr[2] + sr[3];
            __syncthreads();
            float n = sqrtf(tot);
            float v = n / nprev;
            nprev = n;
            float rel = fabsf(v - val) / val;
            val = v;
            k_it += 1.f;
            if (rel < 1e-4f || k_it >= 300.f) break;
        }
    }
    if (tid == 0) {
        float lip2 = val;
        float sigma = expf(log_sigma[0]) + 0.05f;
        float tau = 0.99f / (beta[0] * 0.5f + sigma * lip2);
        ws[WS_LIP2] = lip2;
        ws[WS_TAU] = tau;
        ws[WS_SIGMA] = sigma;
    }
}

// -------------------------------------------------------------------------
// out0 stage 2: sum the NG0 group partials (group order preserves the
// per-group sequential f-summation), apply Dx epilogue, clip [0,1].
// -------------------------------------------------------------------------
__global__ __launch_bounds__(256) void out0_combine_kernel(
    const float* __restrict__ x_in, const float* __restrict__ bias,
    const float* __restrict__ HtH, const float* __restrict__ ws,
    const float* __restrict__ part0, float* __restrict__ out0) {
    const int tid = threadIdx.x;
    const int lane = tid & 63;
    const int wid = tid >> 6;
    const int y = blockIdx.x * 4 + wid;
    const int b = blockIdx.y;
    const int x0 = lane * 4;
    const int p = y * IMW + x0;
    const float tau = ws[WS_TAU];
    float4 ct = {0.f, 0.f, 0.f, 0.f};
#pragma unroll
    for (int g = 0; g < NG0; ++g) {
        const float4 pv = *(const float4*)(part0 + ((size_t)(g * NBT + b)) * HW + p);
        ct.x += pv.x; ct.y += pv.y; ct.z += pv.z; ct.w += pv.w;
    }
    const float4 xi = *(const float4*)(x_in + (size_t)b * HW + p);
    const float4 hh = *(const float4*)(HtH + p);
    const float4 bs = *(const float4*)(bias + (size_t)b * HW + p);
    float4 o;
    o.x = fminf(fmaxf(xi.x - tau * (hh.x * xi.x) - tau * ct.x + tau * bs.x, 0.f), 1.f);
    o.y = fminf(fmaxf(xi.y - tau * (hh.y * xi.y) - tau * ct.y + tau * bs.y, 0.f), 1.f);
    o.z = fminf(fmaxf(xi.z - tau * (hh.z * xi.z) - tau * ct.z + tau * bs.z, 0.f), 1.f);
    o.w = fminf(fmaxf(xi.w - tau * (hh.w * xi.w) - tau * ct.w + tau * bs.w, 0.f), 1.f);
    *(float4*)(out0 + (size_t)b * HW + p) = o;
}

// -------------------------------------------------------------------------
// output1: Du = 2*sigma*conv(out0)_f - sigma*conv(x_in)_f + u; clip [-lam,lam]
// -------------------------------------------------------------------------
__global__ __launch_bounds__(256) void out1_kernel(
    const float* __restrict__ x_in, const float* __restrict__ u_in,
    const float* __restrict__ lambd, const float* __restrict__ w,
    const float* __restrict__ ws, const float* __restrict__ out0,
    float* __restrict__ out1) {
    const int tid = threadIdx.x;
    const int lane = tid & 63;
    const int wid = tid >> 6;
    const int y = blockIdx.x * 4 + wid;
    const int f = blockIdx.y;
    const int b = blockIdx.z;
    const int x0 = lane * 4;
    const float sigma = ws[WS_SIGMA];
    const float lam = lambd[0];
    const float* wf = w + f * 9;
    float wr[9];
#pragma unroll
    for (int i = 0; i < 9; ++i) wr[i] = wf[i];
    const float* o0 = out0 + (size_t)b * HW;
    const float* xb = x_in + (size_t)b * HW;
    float4 s1 = {0.f, 0.f, 0.f, 0.f};
    float4 s2 = {0.f, 0.f, 0.f, 0.f};
#pragma unroll
    for (int dy = -1; dy <= 1; ++dy) {
        int yy = y + dy;
        float4 a = {0.f, 0.f, 0.f, 0.f};
        float4 c = {0.f, 0.f, 0.f, 0.f};
        if ((unsigned)yy < IMH) {
            a = *(const float4*)(o0 + yy * IMW + x0);
            c = *(const float4*)(xb + yy * IMW + x0);
        }
        float am1 = __shfl_up(a.w, 1);  if (lane == 0) am1 = 0.f;
        float ap4 = __shfl_down(a.x, 1); if (lane == 63) ap4 = 0.f;
        float cm1 = __shfl_up(c.w, 1);  if (lane == 0) cm1 = 0.f;
        float cp4 = __shfl_down(c.x, 1); if (lane == 63) cp4 = 0.f;
        const float w0 = wr[(dy + 1) * 3 + 0];
        const float w1 = wr[(dy + 1) * 3 + 1];
        const float w2 = wr[(dy + 1) * 3 + 2];
        s1.x += w0 * am1 + w1 * a.x + w2 * a.y;
        s1.y += w0 * a.x + w1 * a.y + w2 * a.z;
        s1.z += w0 * a.y + w1 * a.z + w2 * a.w;
        s1.w += w0 * a.z + w1 * a.w + w2 * ap4;
        s2.x += w0 * cm1 + w1 * c.x + w2 * c.y;
        s2.y += w0 * c.x + w1 * c.y + w2 * c.z;
        s2.z += w0 * c.y + w1 * c.z + w2 * c.w;
        s2.w += w0 * c.z + w1 * c.w + w2 * cp4;
    }
    const size_t idx = (size_t)(b * NF + f) * HW + y * IMW + x0;
    const float4 uq = *(const float4*)(u_in + idx);
    float4 o;
    o.x = fminf(fmaxf(2.f * sigma * s1.x - sigma * s2.x + uq.x, -lam), lam);
    o.y = fminf(fmaxf(2.f * sigma * s1.y - sigma * s2.y + uq.y, -lam), lam);
    o.z = fminf(fmaxf(2.f * sigma * s1.z - sigma * s2.z + uq.z, -lam), lam);
    o.w = fminf(fmaxf(2.f * sigma * s1.w - sigma * s2.w + uq.w, -lam), lam);
    *(float4*)(out1 + idx) = o;
}

extern "C" void kernel_launch(void* const* d_in, const int* in_sizes, int n_in,
                              void* d_out, int out_size, void* d_ws, size_t ws_size,
                              hipStream_t stream) {
    const float* x_in = (const float*)d_in[0];
    const float* u_in = (const float*)d_in[1];
    const float* bias = (const float*)d_in[2];
    const float* beta = (const float*)d_in[3];
    const float* lambd = (const float*)d_in[4];
    const float* HtH = (const float*)d_in[5];
    const float* w = (const float*)d_in[6];
    const float* log_sigma = (const float*)d_in[7];
    float* ws = (float*)d_ws;
    float* out0 = (float*)d_out;
    float* out1 = out0 + (size_t)NBT * HW;
    // scratch lives in the (not yet written) output1 region:
    //   gbuf: 2*HW floats ping-pong image; part: 300*NPART per-wave partials;
    //   part0: NG0*NBT*HW out0 conv_t group partials (16 MB)
    float* gbuf = out1;
    float* part = out1 + 2 * HW;
    float* part0 = part + (size_t)300 * NPART;

    setup_kernel<<<1, 128, 0, stream>>>(w, ws);
    for (int b = 0; b < NBATCH; ++b)
        pi_batch_kernel<<<256 + OBPB, PIT, 0, stream>>>(ws, gbuf, part, part0, u_in, w, b);
    finalize_kernel<<<1, 256, 0, stream>>>(ws, part, beta, log_sigma);
    out0_combine_kernel<<<dim3(IMH / 4, NBT), 256, 0, stream>>>(x_in, bias, HtH, ws, part0, out0);
    out1_kernel<<<dim3(IMH / 4, NF, NBT), 256, 0, stream>>>(x_in, u_in, lambd, w, ws, out0, out1);
}

// Round 6
// 395.329 us; speedup vs baseline: 1.6918x; 1.6918x over previous
//
#include <hip/hip_runtime.h>
#include <math.h>

#define IMH 256
#define IMW 256
#define NBT 8
#define NF  64
#define HW  65536

// power-iteration batching
#define TSZ 16
#define MB 10          // iterations per batch
#define NBATCH 30      // 30*10 = 300 total
#define HALO (2*MB)    // 20 (operator radius 2 per step)
// LDS buffer: 60 rows x 68 cols (+4 float front guard, +4 tail).
// BROW=68: row stride 272 B -> strips within a wave land 16 banks apart
// (2-way aliasing, free). Data cols in-row [0,64); [64,68) stay zero.
// Region (56x56) at rows [2,58); central 16x16 tile rows [22,38),
// in-row cols [24,40).
#define BROW 68
#define BUFSZ (60*BROW + 8)

// pi_batch: 512 threads (8 waves -> 2 waves/SIMD). 2-row strips, 28 active.
#define PIT 512
#define NPART 2048     // 256 blocks x 8 waves per level

// out0 filter-split (separate wide launch -- R5's per-batch fusion sharded
// this into 30 thin latency-bound slices and cost +250us; never again)
#define NG0 8
#define FG0 (NF / NG0)   // 8 filters per group

// ws float offsets
#define WS_SM   0      // 81: masked-operator table Sm[dr][dq]
#define WS_K5   81     // 25: fused interior 5x5 kernel
#define WS_ET   106    // 5: top-edge correction kernel (applied at gy==0)
#define WS_EB   111    // 5: bottom-edge (gy==IMH-1)
#define WS_EL   116    // 5: left-edge (gx==0, vertical)
#define WS_ER   121    // 5: right-edge (gx==IMW-1, vertical)
#define WS_C4   126    // 4: corner add-backs TL,TR,BL,BR
#define WS_LIP2 431
#define WS_TAU  432
#define WS_SIGMA 433
// incremental stopping-rule state (replayed exactly as reference while_loop)
#define WS_ST_K    434   // iterations consumed so far (float-encoded int)
#define WS_ST_VAL  435   // current val (ratio estimate)
#define WS_ST_STOP 436   // 1.0f once rel<1e-4 or k>=300

// -------------------------------------------------------------------------
// Setup: build Sm, K5, and edge-correction tables from w.
// -------------------------------------------------------------------------
__global__ void setup_kernel(const float* __restrict__ w, float* __restrict__ ws) {
    int t = threadIdx.x;
    __shared__ float smS[81];
    if (t < 81) {
        int a = t / 9, bq = t % 9;
        int dry = a / 3 - 1, drx = a % 3 - 1;
        int dqy = bq / 3 - 1, dqx = bq % 3 - 1;
        int r_idx = (1 - dry) * 3 + (1 - drx);
        int q_idx = (dqy + 1) * 3 + (dqx + 1);
        float s = 0.f;
        for (int f = 0; f < NF; ++f) s += w[f * 9 + r_idx] * w[f * 9 + q_idx];
        smS[t] = s;
        ws[WS_SM + t] = s;
    }
    __syncthreads();
    if (t < 25) {
        int dy = t / 5 - 2, dx = t % 5 - 2;
        float k = 0.f;
        for (int a = 0; a < 9; ++a) {
            int dry = a / 3 - 1, drx = a % 3 - 1;
            for (int bq = 0; bq < 9; ++bq) {
                int dqy = bq / 3 - 1, dqx = bq % 3 - 1;
                if (dry + dqy == dy && drx + dqx == dx) k += smS[a * 9 + bq];
            }
        }
        ws[WS_K5 + t] = k;
    }
    if (t == 0) {
        for (int dd = 0; dd < 5; ++dd) {
            int dx = dd - 2;
            float et = 0.f, eb = 0.f, el = 0.f, er = 0.f;
            for (int dr = -1; dr <= 1; ++dr) {
                int dq = dx - dr;
                if (dq < -1 || dq > 1) continue;
                et += smS[(0 * 3 + dr + 1) * 9 + (2 * 3 + dq + 1)];   // dry=-1,dqy=+1
                eb += smS[(2 * 3 + dr + 1) * 9 + (0 * 3 + dq + 1)];   // dry=+1,dqy=-1
                el += smS[((dr + 1) * 3 + 0) * 9 + ((dq + 1) * 3 + 2)]; // drx=-1,dqx=+1
                er += smS[((dr + 1) * 3 + 2) * 9 + ((dq + 1) * 3 + 0)]; // drx=+1,dqx=-1
            }
            ws[WS_ET + dd] = et;
            ws[WS_EB + dd] = eb;
            ws[WS_EL + dd] = el;
            ws[WS_ER + dd] = er;
        }
        ws[WS_C4 + 0] = smS[0 * 9 + 8];  // TL
        ws[WS_C4 + 1] = smS[2 * 9 + 6];  // TR
        ws[WS_C4 + 2] = smS[6 * 9 + 2];  // BL
        ws[WS_C4 + 3] = smS[8 * 9 + 0];  // BR
        // re-init convergence state every launch (re-poison safety)
        ws[WS_ST_K] = 0.f;
        ws[WS_ST_VAL] = 1.0f;
        ws[WS_ST_STOP] = 0.f;
    }
}

// -------------------------------------------------------------------------
// One batch of MB power-iteration steps. 256 blocks = 16x16 tiles.
// 512 threads: strip = tid>>4 (2 output rows each, 28 active of 32),
// q = tid&15 (4-col quad). Per step: 6x8 register window, 200 FMAs,
// edge corrections, zero-outside mask, 2 b128 writes.
// Dependency-cone skip at 8-row wave granularity (bit-exact).
// Early exit: block 0 folds the PREVIOUS batch's 10 level norms into the
// stopping-rule state (1-batch lag); once stopped, blocks return (~2us).
// -------------------------------------------------------------------------
__global__ __launch_bounds__(PIT) void pi_batch_kernel(
    float* __restrict__ ws, float* __restrict__ gbuf,
    float* __restrict__ part, int batch) {
    __shared__ float bufA[BUFSZ];
    __shared__ float bufB[BUFSZ];
    __shared__ float sred[8];
    const int tid = threadIdx.x;
    const int bid = blockIdx.x;
    const int wid = tid >> 6;
    const int lane = tid & 63;
    const int q = tid & 15;
    const int strip = tid >> 4;
    const int tx = bid & 15;
    const int ty = bid >> 4;
    const float* gin = gbuf + ((batch & 1) ? HW : 0);
    float* gout      = gbuf + ((batch & 1) ? 0 : HW);

    // converged already? (state covers levels <= (batch-1)*MB)
    if (batch > 0 && ws[WS_ST_STOP] != 0.f) return;

    // block 0: fold batch-1's levels into the stopping-rule state.
    if (bid == 0 && batch > 0) {
        float k_it = ws[WS_ST_K];
        float val  = ws[WS_ST_VAL];
        float nprev = 1.0f;
        float newstop = 0.f;
        const float* pb = part + (size_t)((batch - 1) * MB) * NPART;
        for (int s = 0; s < MB; ++s) {
            const float* pp = pb + (size_t)s * NPART;
            float sm = pp[tid] + pp[tid + 512] + pp[tid + 1024] + pp[tid + 1536];
#pragma unroll
            for (int o = 32; o > 0; o >>= 1) sm += __shfl_down(sm, o, 64);
            if (lane == 0) sred[wid] = sm;
            __syncthreads();
            float tot = sred[0] + sred[1] + sred[2] + sred[3]
                      + sred[4] + sred[5] + sred[6] + sred[7];
            __syncthreads();
            float n = sqrtf(tot);
            float v = n / nprev;
            nprev = n;
            float rel = fabsf(v - val) / val;
            val = v;
            k_it += 1.f;
            if (rel < 1e-4f || k_it >= 300.f) { newstop = 1.f; break; }
        }
        if (tid == 0) {
            ws[WS_ST_K] = k_it;
            ws[WS_ST_VAL] = val;
            ws[WS_ST_STOP] = newstop;
        }
        __syncthreads();
    }

    float k5[25];
#pragma unroll
    for (int i = 0; i < 25; ++i) k5[i] = ws[WS_K5 + i];
    float et[5], eb[5], el[5], er[5], c4[4];
#pragma unroll
    for (int i = 0; i < 5; ++i) {
        et[i] = ws[WS_ET + i]; eb[i] = ws[WS_EB + i];
        el[i] = ws[WS_EL + i]; er[i] = ws[WS_ER + i];
    }
#pragma unroll
    for (int i = 0; i < 4; ++i) c4[i] = ws[WS_C4 + i];

    float inv_n;
    if (batch == 0) {
        inv_n = 1.0f / 256.0f;
    } else {
        const float* pp = part + (size_t)(batch * MB - 1) * NPART;
        float s = pp[tid] + pp[tid + 512] + pp[tid + 1024] + pp[tid + 1536];
#pragma unroll
        for (int o = 32; o > 0; o >>= 1) s += __shfl_down(s, o, 64);
        if (lane == 0) sred[wid] = s;
        __syncthreads();
        inv_n = 1.0f / sqrtf(sred[0] + sred[1] + sred[2] + sred[3]
                           + sred[4] + sred[5] + sred[6] + sred[7]);
        __syncthreads();
    }

    // load region into bufA (zeros outside image / in pads); zero bufB fully
    for (int i = tid; i < BUFSZ; i += PIT) {
        float v = 0.f;
        if (i >= 4) {
            int cell = i - 4;
            int r = cell / BROW, c = cell - r * BROW;
            if (r < 60 && c < 64) {
                int gy = ty * 16 - 22 + r;    // region row r-2 + oy
                int gx = tx * 16 - 24 + c;    // region col c-4 + ox
                if ((unsigned)gy < IMH && (unsigned)gx < IMW)
                    v = (batch == 0) ? inv_n : gin[gy * IMW + gx] * inv_n;
            }
        }
        bufA[i] = v;
        bufB[i] = 0.f;
    }
    __syncthreads();

    // per-thread invariants (2-row strips)
    const bool active = (strip < 28);
    const int r0 = 2 + 2 * strip;          // output rows r0, r0+1
    const int gy0 = ty * 16 - 22 + r0;
    const int gx0 = tx * 16 - 24 + 4 * q;
    bool iny[2], bt[2], bb[2];
#pragma unroll
    for (int k = 0; k < 2; ++k) {
        int gy = gy0 + k;
        iny[k] = ((unsigned)gy < IMH);
        bt[k] = (gy == 0);
        bb[k] = (gy == IMH - 1);
    }
    bool inx[4];
#pragma unroll
    for (int i = 0; i < 4; ++i) inx[i] = ((unsigned)(gx0 + i) < IMW);
    const bool bL = (gx0 == 0);
    const bool bR = (gx0 + 3 == IMW - 1);
    const bool central = (q >= 6 && q < 10) && (strip >= 10 && strip < 18);
    // wave row band for dependency-cone skip (8 rows per wave)
    const int wrow_lo = 2 + 8 * wid;
    const int wrow_hi = (wrow_lo + 8 < 58) ? wrow_lo + 8 : 58;

    float* cur = bufA;
    float* nxt = bufB;
#pragma unroll 1
    for (int s = 0; s < MB; ++s) {
        float pv = 0.f;
        // needed rows after this step: [2+2*(s+1), 58-2*(s+1))
        const int lo = 2 + 2 * (s + 1);
        const int hi = 58 - 2 * (s + 1);
        const bool wave_need = (wrow_lo < hi) && (wrow_hi > lo);
        if (active && wave_need) {
            // 6x8 register window: rows r0-2 .. r0+3, cols 4q-2 .. 4q+5
            float win[6][8];
            const int base = 4 + (r0 - 2) * BROW + 4 * q;
#pragma unroll
            for (int m = 0; m < 6; ++m) {
                float4 a = *(const float4*)&cur[base + m * BROW];
                float2 lo2 = *(const float2*)&cur[base + m * BROW - 2];
                float2 hi2 = *(const float2*)&cur[base + m * BROW + 4];
                win[m][0] = lo2.x; win[m][1] = lo2.y;
                win[m][2] = a.x;  win[m][3] = a.y;
                win[m][4] = a.z;  win[m][5] = a.w;
                win[m][6] = hi2.x; win[m][7] = hi2.y;
            }
            float z[2][4];
#pragma unroll
            for (int k = 0; k < 2; ++k) {
#pragma unroll
                for (int i = 0; i < 4; ++i) z[k][i] = 0.f;
#pragma unroll
                for (int j = 0; j < 5; ++j) {
#pragma unroll
                    for (int dx = 0; dx < 5; ++dx) {
                        const float kv = k5[j * 5 + dx];
                        z[k][0] += kv * win[k + j][0 + dx];
                        z[k][1] += kv * win[k + j][1 + dx];
                        z[k][2] += kv * win[k + j][2 + dx];
                        z[k][3] += kv * win[k + j][3 + dx];
                    }
                }
            }
            // image-edge corrections (outermost ring only)
#pragma unroll
            for (int k = 0; k < 2; ++k) {
                if (bt[k]) {
#pragma unroll
                    for (int i = 0; i < 4; ++i) {
                        float c = 0.f;
#pragma unroll
                        for (int d = 0; d < 5; ++d) c += et[d] * win[k + 2][i + d];
                        z[k][i] -= c;
                    }
                }
                if (bb[k]) {
#pragma unroll
                    for (int i = 0; i < 4; ++i) {
                        float c = 0.f;
#pragma unroll
                        for (int d = 0; d < 5; ++d) c += eb[d] * win[k + 2][i + d];
                        z[k][i] -= c;
                    }
                }
            }
            if (bL) {
#pragma unroll
                for (int k = 0; k < 2; ++k) {
                    float c = 0.f;
#pragma unroll
                    for (int j = 0; j < 5; ++j) c += el[j] * win[k + j][2];
                    z[k][0] -= c;
                    if (bt[k]) z[k][0] += c4[0] * win[k + 2][2];
                    if (bb[k]) z[k][0] += c4[2] * win[k + 2][2];
                }
            }
            if (bR) {
#pragma unroll
                for (int k = 0; k < 2; ++k) {
                    float c = 0.f;
#pragma unroll
                    for (int j = 0; j < 5; ++j) c += er[j] * win[k + j][5];
                    z[k][3] -= c;
                    if (bt[k]) z[k][3] += c4[1] * win[k + 2][5];
                    if (bb[k]) z[k][3] += c4[3] * win[k + 2][5];
                }
            }
            // zero-outside mask, store, central-norm partial
#pragma unroll
            for (int k = 0; k < 2; ++k) {
                float4 o;
                o.x = (iny[k] && inx[0]) ? z[k][0] : 0.f;
                o.y = (iny[k] && inx[1]) ? z[k][1] : 0.f;
                o.z = (iny[k] && inx[2]) ? z[k][2] : 0.f;
                o.w = (iny[k] && inx[3]) ? z[k][3] : 0.f;
                *(float4*)&nxt[4 + (r0 + k) * BROW + 4 * q] = o;
                if (central)
                    pv += o.x * o.x + o.y * o.y + o.z * o.z + o.w * o.w;
            }
        }
        // per-wave reduce; wave leader stores to its private slot
#pragma unroll
        for (int o = 32; o > 0; o >>= 1) pv += __shfl_down(pv, o, 64);
        if (lane == 0)
            part[(size_t)(batch * MB + s) * NPART + (bid << 3) + wid] = pv;
        __syncthreads();
        float* tmp = cur; cur = nxt; nxt = tmp;
    }

    // write central 16x16 tile (64 threads x float4)
    if (tid < 64) {
        int rr = tid >> 2, cq = tid & 3;
        float4 v = *(const float4*)&cur[4 + (22 + rr) * BROW + 24 + 4 * cq];
        int gy = ty * 16 + rr, gx = tx * 16 + 4 * cq;
        *(float4*)&gout[gy * IMW + gx] = v;
    }
}

// -------------------------------------------------------------------------
// Finalize: fold the LAST batch's levels (if the rule hasn't stopped yet),
// then compute tau/sigma.
// -------------------------------------------------------------------------
__global__ __launch_bounds__(256) void finalize_kernel(
    float* __restrict__ ws, const float* __restrict__ part,
    const float* __restrict__ beta, const float* __restrict__ log_sigma) {
    __shared__ float sr[4];
    const int tid = threadIdx.x;
    const int lane = tid & 63;
    const int wid = tid >> 6;
    float k_it = ws[WS_ST_K];
    float val  = ws[WS_ST_VAL];
    const float stop = ws[WS_ST_STOP];
    if (stop == 0.f) {
        float nprev = 1.0f;
        const float* pb = part + (size_t)((NBATCH - 1) * MB) * NPART;
        for (int s = 0; s < MB; ++s) {
            const float* pp = pb + (size_t)s * NPART;
            float sm = 0.f;
#pragma unroll
            for (int j = 0; j < 8; ++j) sm += pp[tid + 256 * j];
#pragma unroll
            for (int o = 32; o > 0; o >>= 1) sm += __shfl_down(sm, o, 64);
            if (lane == 0) sr[wid] = sm;
            __syncthreads();
            float tot = sr[0] + sr[1] + sr[2] + sr[3];
            __syncthreads();
            float n = sqrtf(tot);
            float v = n / nprev;
            nprev = n;
            float rel = fabsf(v - val) / val;
            val = v;
            k_it += 1.f;
            if (rel < 1e-4f || k_it >= 300.f) break;
        }
    }
    if (tid == 0) {
        float lip2 = val;
        float sigma = expf(log_sigma[0]) + 0.05f;
        float tau = 0.99f / (beta[0] * 0.5f + sigma * lip2);
        ws[WS_LIP2] = lip2;
        ws[WS_TAU] = tau;
        ws[WS_SIGMA] = sigma;
    }
}

// -------------------------------------------------------------------------
// out0 stage 1: partial conv_t over an 8-filter group.
// grid (IMH/4, NG0, NBT) -> 4096 blocks (one wide launch).
// wave = one image row; lane = 4-px quad (float4); x-halo via shuffles.
// part0 layout: [(g*NBT + b)*HW + p]
// -------------------------------------------------------------------------
__global__ __launch_bounds__(256) void out0_part_kernel(
    const float* __restrict__ u_in, const float* __restrict__ w,
    float* __restrict__ part0) {
    const int tid = threadIdx.x;
    const int lane = tid & 63;
    const int wid = tid >> 6;
    const int y = blockIdx.x * 4 + wid;
    const int g = blockIdx.y;
    const int b = blockIdx.z;
    const int x0 = lane * 4;
    float4 ct = {0.f, 0.f, 0.f, 0.f};
    const float* ub = u_in + ((size_t)b * NF + g * FG0) * HW;
    const float* wg = w + g * FG0 * 9;
#pragma unroll 4
    for (int f = 0; f < FG0; ++f) {
        const float* uf = ub + (size_t)f * HW;
        const float* wf = wg + f * 9;
#pragma unroll
        for (int dy = -1; dy <= 1; ++dy) {
            int yy = y + dy;
            float4 v = {0.f, 0.f, 0.f, 0.f};
            if ((unsigned)yy < IMH)
                v = *(const float4*)(uf + yy * IMW + x0);
            float m1 = __shfl_up(v.w, 1);
            if (lane == 0) m1 = 0.f;
            float p4 = __shfl_down(v.x, 1);
            if (lane == 63) p4 = 0.f;
            const float w2 = wf[(1 - dy) * 3 + 2];   // dx=-1
            const float w1 = wf[(1 - dy) * 3 + 1];   // dx= 0
            const float w0 = wf[(1 - dy) * 3 + 0];   // dx=+1
            ct.x += w2 * m1  + w1 * v.x + w0 * v.y;
            ct.y += w2 * v.x + w1 * v.y + w0 * v.z;
            ct.z += w2 * v.y + w1 * v.z + w0 * v.w;
            ct.w += w2 * v.z + w1 * v.w + w0 * p4;
        }
    }
    *(float4*)(part0 + ((size_t)(g * NBT + b)) * HW + y * IMW + x0) = ct;
}

// -------------------------------------------------------------------------
// out0 stage 2: sum the NG0 group partials (group order preserves the
// per-group sequential f-summation), apply Dx epilogue, clip [0,1].
// -------------------------------------------------------------------------
__global__ __launch_bounds__(256) void out0_combine_kernel(
    const float* __restrict__ x_in, const float* __restrict__ bias,
    const float* __restrict__ HtH, const float* __restrict__ ws,
    const float* __restrict__ part0, float* __restrict__ out0) {
    const int tid = threadIdx.x;
    const int lane = tid & 63;
    const int wid = tid >> 6;
    const int y = blockIdx.x * 4 + wid;
    const int b = blockIdx.y;
    const int x0 = lane * 4;
    const int p = y * IMW + x0;
    const float tau = ws[WS_TAU];
    float4 ct = {0.f, 0.f, 0.f, 0.f};
#pragma unroll
    for (int g = 0; g < NG0; ++g) {
        const float4 pv = *(const float4*)(part0 + ((size_t)(g * NBT + b)) * HW + p);
        ct.x += pv.x; ct.y += pv.y; ct.z += pv.z; ct.w += pv.w;
    }
    const float4 xi = *(const float4*)(x_in + (size_t)b * HW + p);
    const float4 hh = *(const float4*)(HtH + p);
    const float4 bs = *(const float4*)(bias + (size_t)b * HW + p);
    float4 o;
    o.x = fminf(fmaxf(xi.x - tau * (hh.x * xi.x) - tau * ct.x + tau * bs.x, 0.f), 1.f);
    o.y = fminf(fmaxf(xi.y - tau * (hh.y * xi.y) - tau * ct.y + tau * bs.y, 0.f), 1.f);
    o.z = fminf(fmaxf(xi.z - tau * (hh.z * xi.z) - tau * ct.z + tau * bs.z, 0.f), 1.f);
    o.w = fminf(fmaxf(xi.w - tau * (hh.w * xi.w) - tau * ct.w + tau * bs.w, 0.f), 1.f);
    *(float4*)(out0 + (size_t)b * HW + p) = o;
}

// -------------------------------------------------------------------------
// output1: Du = 2*sigma*conv(out0)_f - sigma*conv(x_in)_f + u; clip [-lam,lam]
// -------------------------------------------------------------------------
__global__ __launch_bounds__(256) void out1_kernel(
    const float* __restrict__ x_in, const float* __restrict__ u_in,
    const float* __restrict__ lambd, const float* __restrict__ w,
    const float* __restrict__ ws, const float* __restrict__ out0,
    float* __restrict__ out1) {
    const int tid = threadIdx.x;
    const int lane = tid & 63;
    const int wid = tid >> 6;
    const int y = blockIdx.x * 4 + wid;
    const int f = blockIdx.y;
    const int b = blockIdx.z;
    const int x0 = lane * 4;
    const float sigma = ws[WS_SIGMA];
    const float lam = lambd[0];
    const float* wf = w + f * 9;
    float wr[9];
#pragma unroll
    for (int i = 0; i < 9; ++i) wr[i] = wf[i];
    const float* o0 = out0 + (size_t)b * HW;
    const float* xb = x_in + (size_t)b * HW;
    float4 s1 = {0.f, 0.f, 0.f, 0.f};
    float4 s2 = {0.f, 0.f, 0.f, 0.f};
#pragma unroll
    for (int dy = -1; dy <= 1; ++dy) {
        int yy = y + dy;
        float4 a = {0.f, 0.f, 0.f, 0.f};
        float4 c = {0.f, 0.f, 0.f, 0.f};
        if ((unsigned)yy < IMH) {
            a = *(const float4*)(o0 + yy * IMW + x0);
            c = *(const float4*)(xb + yy * IMW + x0);
        }
        float am1 = __shfl_up(a.w, 1);  if (lane == 0) am1 = 0.f;
        float ap4 = __shfl_down(a.x, 1); if (lane == 63) ap4 = 0.f;
        float cm1 = __shfl_up(c.w, 1);  if (lane == 0) cm1 = 0.f;
        float cp4 = __shfl_down(c.x, 1); if (lane == 63) cp4 = 0.f;
        const float w0 = wr[(dy + 1) * 3 + 0];
        const float w1 = wr[(dy + 1) * 3 + 1];
        const float w2 = wr[(dy + 1) * 3 + 2];
        s1.x += w0 * am1 + w1 * a.x + w2 * a.y;
        s1.y += w0 * a.x + w1 * a.y + w2 * a.z;
        s1.z += w0 * a.y + w1 * a.z + w2 * a.w;
        s1.w += w0 * a.z + w1 * a.w + w2 * ap4;
        s2.x += w0 * cm1 + w1 * c.x + w2 * c.y;
        s2.y += w0 * c.x + w1 * c.y + w2 * c.z;
        s2.z += w0 * c.y + w1 * c.z + w2 * c.w;
        s2.w += w0 * c.z + w1 * c.w + w2 * cp4;
    }
    const size_t idx = (size_t)(b * NF + f) * HW + y * IMW + x0;
    const float4 uq = *(const float4*)(u_in + idx);
    float4 o;
    o.x = fminf(fmaxf(2.f * sigma * s1.x - sigma * s2.x + uq.x, -lam), lam);
    o.y = fminf(fmaxf(2.f * sigma * s1.y - sigma * s2.y + uq.y, -lam), lam);
    o.z = fminf(fmaxf(2.f * sigma * s1.z - sigma * s2.z + uq.z, -lam), lam);
    o.w = fminf(fmaxf(2.f * sigma * s1.w - sigma * s2.w + uq.w, -lam), lam);
    *(float4*)(out1 + idx) = o;
}

extern "C" void kernel_launch(void* const* d_in, const int* in_sizes, int n_in,
                              void* d_out, int out_size, void* d_ws, size_t ws_size,
                              hipStream_t stream) {
    const float* x_in = (const float*)d_in[0];
    const float* u_in = (const float*)d_in[1];
    const float* bias = (const float*)d_in[2];
    const float* beta = (const float*)d_in[3];
    const float* lambd = (const float*)d_in[4];
    const float* HtH = (const float*)d_in[5];
    const float* w = (const float*)d_in[6];
    const float* log_sigma = (const float*)d_in[7];
    float* ws = (float*)d_ws;
    float* out0 = (float*)d_out;
    float* out1 = out0 + (size_t)NBT * HW;
    // scratch lives in the (not yet written) output1 region:
    //   gbuf: 2*HW floats ping-pong image; part: 300*NPART per-wave partials;
    //   part0: NG0*NBT*HW out0 conv_t group partials (16 MB)
    float* gbuf = out1;
    float* part = out1 + 2 * HW;
    float* part0 = part + (size_t)300 * NPART;

    setup_kernel<<<1, 128, 0, stream>>>(w, ws);
    for (int b = 0; b < NBATCH; ++b)
        pi_batch_kernel<<<256, PIT, 0, stream>>>(ws, gbuf, part, b);
    finalize_kernel<<<1, 256, 0, stream>>>(ws, part, beta, log_sigma);
    out0_part_kernel<<<dim3(IMH / 4, NG0, NBT), 256, 0, stream>>>(u_in, w, part0);
    out0_combine_kernel<<<dim3(IMH / 4, NBT), 256, 0, stream>>>(x_in, bias, HtH, ws, part0, out0);
    out1_kernel<<<dim3(IMH / 4, NF, NBT), 256, 0, stream>>>(x_in, u_in, lambd, w, ws, out0, out1);
}